// Round 3
// baseline (182.923 us; speedup 1.0000x reference)
//
#include <hip/hip_runtime.h>
#include <hip/hip_bf16.h>

typedef __attribute__((ext_vector_type(4))) float f32x4;
typedef __attribute__((ext_vector_type(8))) short bf16x8;

#define M_TOT 30752   // 8*62*62 output pixels

__device__ __forceinline__ unsigned short f2bf(float f) {
  unsigned int u = __float_as_uint(f);
  u = u + 0x7FFF + ((u >> 16) & 1);   // round-to-nearest-even
  return (unsigned short)(u >> 16);
}

// ---- prep 1: cast x (fp32) -> bf16, 8 elems/thread ----
__global__ void cast_x(const float* __restrict__ x, unsigned short* __restrict__ xb) {
  int i = blockIdx.x * 256 + threadIdx.x;
  const f32x4* xp = (const f32x4*)x;
  f32x4 a = xp[2 * i];
  f32x4 b = xp[2 * i + 1];
  bf16x8 o;
  o[0] = (short)f2bf(a[0]); o[1] = (short)f2bf(a[1]);
  o[2] = (short)f2bf(a[2]); o[3] = (short)f2bf(a[3]);
  o[4] = (short)f2bf(b[0]); o[5] = (short)f2bf(b[1]);
  o[6] = (short)f2bf(b[2]); o[7] = (short)f2bf(b[3]);
  ((bf16x8*)xb)[i] = o;
}

// ---- prep 2: K_eff[och][kk][f] = sum_bi Q[och,kk,bi] * S[16bi+(och>>4)][och&15][f]
__global__ void keff_k(const float* __restrict__ Q, const float* __restrict__ S,
                       float* __restrict__ Keff) {
  int bid = blockIdx.x;          // = och*9 + kk
  int o = bid / 9;
  int kk = bid - o * 9;
  int f = threadIdx.x;
  int qb = o * 144 + kk * 16;
  int sb = ((o >> 4) * 16 + (o & 15)) * 256 + f;
  float acc = 0.f;
#pragma unroll
  for (int bi = 0; bi < 16; ++bi)
    acc = fmaf(Q[qb + bi], S[sb + bi * 65536], acc);
  Keff[bid * 256 + f] = acc;
}

// ---- prep 3: K2t[kk][f][ci] = sum_o P[o][ci] * Keff[o][kk][f]  (bf16, transposed)
__global__ void k2t_k(const float* __restrict__ P, const float* __restrict__ Keff,
                      unsigned short* __restrict__ K2t) {
  int kk = blockIdx.x >> 4;
  int f0 = (blockIdx.x & 15) * 16;
  int ci = threadIdx.x;
  float acc[16];
#pragma unroll
  for (int j = 0; j < 16; ++j) acc[j] = 0.f;
  for (int o = 0; o < 256; ++o) {
    float pv = P[o * 256 + ci];
    const float* ke = Keff + (o * 9 + kk) * 256 + f0;
#pragma unroll
    for (int j = 0; j < 16; ++j) acc[j] = fmaf(pv, ke[j], acc[j]);
  }
#pragma unroll
  for (int j = 0; j < 16; ++j)
    K2t[kk * 65536 + (f0 + j) * 256 + ci] = f2bf(acc[j]);
}

// ---- main: implicit-GEMM conv, NO LDS, direct global->register fragments.
// M=30752, N=256, K=2304. Block = 512 thr (8 waves, 2m x 4n), per-wave 64x64 out.
// B (K2t, 1.2MB) is L2-resident; A (xb, 16.8MB) is L2/L3-resident. Fragment
// loads are 16 rows x 128B = full cache lines, served by L2 at ~135 B/cy/CU
// (< MFMA's 1240 cy/iter). No barriers: 8 independent waves hide latency.
__global__ __launch_bounds__(512, 2) void conv_gemm(const unsigned short* __restrict__ xb,
                                                    const unsigned short* __restrict__ K2t,
                                                    float* __restrict__ out) {
  const int tid = threadIdx.x;
  const int lane = tid & 63;
  const int wm = (tid >> 6) >> 2;   // 0..1
  const int wn = (tid >> 6) & 3;    // 0..3
  const int m0 = blockIdx.x * 128;

  const int rl = lane & 15;         // fragment row (A: pixel; B: filter)
  const int kg = lane >> 4;         // k-group 0..3 (8 consecutive k-elems each)

  // per-mi A pixel base addresses (elements into xb), k-group offset folded in
  int aBase[4];
#pragma unroll
  for (int mi = 0; mi < 4; ++mi) {
    int m = m0 + wm * 64 + mi * 16 + rl;
    if (m >= M_TOT) m = M_TOT - 1;          // clamp (dup read, store guarded)
    int b = m / 3844; int rem = m - b * 3844;
    int h = rem / 62; int w = rem - h * 62;
    aBase[mi] = ((b * 64 + h) * 64 + w) * 256 + kg * 8;
  }
  // per-ni B row bases (elements into K2t)
  int bBase[4];
#pragma unroll
  for (int ni = 0; ni < 4; ++ni)
    bBase[ni] = (wn * 64 + ni * 16 + rl) * 256 + kg * 8;

  f32x4 zero = {0.f, 0.f, 0.f, 0.f};
  f32x4 acc[4][4];
#pragma unroll
  for (int i = 0; i < 4; ++i)
#pragma unroll
    for (int j = 0; j < 4; ++j) acc[i][j] = zero;

  for (int kk = 0; kk < 9; ++kk) {
    int kh = kk / 3;
    int kw = kk - kh * 3;
    int offA = kh * 16384 + kw * 256;   // elements
    int offB = kk * 65536;
#pragma unroll
    for (int cb = 0; cb < 4; ++cb) {
      int oA = offA + cb * 64;
      int oB = offB + cb * 64;
      bf16x8 af[4][2], bfr[4][2];
#pragma unroll
      for (int mi = 0; mi < 4; ++mi)
#pragma unroll
        for (int ks = 0; ks < 2; ++ks)
          af[mi][ks] = *(const bf16x8*)(xb + aBase[mi] + oA + ks * 32);
#pragma unroll
      for (int ni = 0; ni < 4; ++ni)
#pragma unroll
        for (int ks = 0; ks < 2; ++ks)
          bfr[ni][ks] = *(const bf16x8*)(K2t + bBase[ni] + oB + ks * 32);
#pragma unroll
      for (int ks = 0; ks < 2; ++ks)
#pragma unroll
        for (int mi = 0; mi < 4; ++mi)
#pragma unroll
          for (int ni = 0; ni < 4; ++ni)
            acc[mi][ni] = __builtin_amdgcn_mfma_f32_16x16x32_bf16(
                af[mi][ks], bfr[ni][ks], acc[mi][ni], 0, 0, 0);
    }
  }

  // epilogue: D row = kg*4 + r (+16*mi +64*wm), col = rl (+16*ni +64*wn)
#pragma unroll
  for (int mi = 0; mi < 4; ++mi) {
    int mb = m0 + wm * 64 + mi * 16 + kg * 4;
#pragma unroll
    for (int ni = 0; ni < 4; ++ni) {
      int f = wn * 64 + ni * 16 + rl;
#pragma unroll
      for (int r = 0; r < 4; ++r) {
        int m = mb + r;
        if (m < M_TOT) out[m * 256 + f] = acc[mi][ni][r];
      }
    }
  }
}

extern "C" void kernel_launch(void* const* d_in, const int* in_sizes, int n_in,
                              void* d_out, int out_size, void* d_ws, size_t ws_size,
                              hipStream_t stream) {
  const float* x = (const float*)d_in[0];   // [8,64,64,256]
  const float* P = (const float*)d_in[1];   // [256,256]
  const float* Q = (const float*)d_in[2];   // [256,3,3,16]
  const float* S = (const float*)d_in[3];   // [256,16,256]
  float* out = (float*)d_out;               // [8,62,62,256]

  char* ws = (char*)d_ws;
  unsigned short* xb   = (unsigned short*)ws;                        // 16,777,216 B
  float*          Keff = (float*)(ws + 16777216);                    //  2,359,296 B
  unsigned short* K2t  = (unsigned short*)(ws + 16777216 + 2359296); //  1,179,648 B

  cast_x<<<4096, 256, 0, stream>>>(x, xb);
  keff_k<<<2304, 256, 0, stream>>>(Q, S, Keff);
  k2t_k<<<144, 256, 0, stream>>>(P, Keff, K2t);
  conv_gemm<<<241, 512, 0, stream>>>(xb, K2t, out);
}

// Round 4
// 101.285 us; speedup vs baseline: 1.8060x; 1.8060x over previous
//
#include <hip/hip_runtime.h>
#include <hip/hip_bf16.h>

typedef __attribute__((ext_vector_type(4))) float f32x4;
typedef __attribute__((ext_vector_type(8))) short bf16x8;

#define M_TOT 30752   // 8*62*62 output pixels

__device__ __forceinline__ unsigned short f2bf(float f) {
  unsigned int u = __float_as_uint(f);
  u = u + 0x7FFF + ((u >> 16) & 1);   // round-to-nearest-even
  return (unsigned short)(u >> 16);
}

__device__ __forceinline__ void gload16(const void* g, void* l) {
  __builtin_amdgcn_global_load_lds((const __attribute__((address_space(1))) unsigned int*)g,
                                   (__attribute__((address_space(3))) unsigned int*)l,
                                   16, 0, 0);
}

// ---- prep 1: cast x (fp32) -> bf16, 8 elems/thread ----
__global__ void cast_x(const float* __restrict__ x, unsigned short* __restrict__ xb) {
  int i = blockIdx.x * 256 + threadIdx.x;
  const f32x4* xp = (const f32x4*)x;
  f32x4 a = xp[2 * i];
  f32x4 b = xp[2 * i + 1];
  bf16x8 o;
  o[0] = (short)f2bf(a[0]); o[1] = (short)f2bf(a[1]);
  o[2] = (short)f2bf(a[2]); o[3] = (short)f2bf(a[3]);
  o[4] = (short)f2bf(b[0]); o[5] = (short)f2bf(b[1]);
  o[6] = (short)f2bf(b[2]); o[7] = (short)f2bf(b[3]);
  ((bf16x8*)xb)[i] = o;
}

// ---- prep 2: K_eff[och][kk][f] = sum_bi Q[och,kk,bi] * S[16bi+(och>>4)][och&15][f]
__global__ void keff_k(const float* __restrict__ Q, const float* __restrict__ S,
                       float* __restrict__ Keff) {
  int bid = blockIdx.x;          // = och*9 + kk
  int o = bid / 9;
  int kk = bid - o * 9;
  int f = threadIdx.x;
  int qb = o * 144 + kk * 16;
  int sb = ((o >> 4) * 16 + (o & 15)) * 256 + f;
  float acc = 0.f;
#pragma unroll
  for (int bi = 0; bi < 16; ++bi)
    acc = fmaf(Q[qb + bi], S[sb + bi * 65536], acc);
  Keff[bid * 256 + f] = acc;
}

// ---- prep 3: K2t[kk][f][ci] = sum_o P[o][ci] * Keff[o][kk][f]  (bf16, transposed)
__global__ void k2t_k(const float* __restrict__ P, const float* __restrict__ Keff,
                      unsigned short* __restrict__ K2t) {
  int kk = blockIdx.x >> 4;
  int f0 = (blockIdx.x & 15) * 16;
  int ci = threadIdx.x;
  float acc[16];
#pragma unroll
  for (int j = 0; j < 16; ++j) acc[j] = 0.f;
  for (int o = 0; o < 256; ++o) {
    float pv = P[o * 256 + ci];
    const float* ke = Keff + (o * 9 + kk) * 256 + f0;
#pragma unroll
    for (int j = 0; j < 16; ++j) acc[j] = fmaf(pv, ke[j], acc[j]);
  }
#pragma unroll
  for (int j = 0; j < 16; ++j)
    K2t[kk * 65536 + (f0 + j) * 256 + ci] = f2bf(acc[j]);
}

// ---- main: implicit-GEMM conv.  M=30752, N=256 (full), K=2304 (9 taps x 256 ch)
// BM=128, BN=256, BK=64. 512 thr (8 waves, 2m x 4n), 64x64 out per wave.
// R1 tile/locality (FETCH ~20MB) + true 2-phase double-buffer (T3-minimum):
// STAGE(t+1)->buf^1 issued BEFORE compute(t); one barrier per K-step whose
// vmcnt(0) drain waits on loads issued ~1030cy of MFMA earlier (L2 covered).
__global__ __launch_bounds__(512) void conv_gemm(const unsigned short* __restrict__ xb,
                                                 const unsigned short* __restrict__ K2t,
                                                 float* __restrict__ out) {
  __shared__ unsigned short ldsA[2][128 * 64];   // 2 x 16KB, XOR-swizzled
  __shared__ unsigned short ldsB[2][256 * 64];   // 2 x 32KB, XOR-swizzled

  const int tid = threadIdx.x;
  const int lane = tid & 63;
  const int wm = (tid >> 6) >> 2;   // 0..1
  const int wn = (tid >> 6) & 3;    // 0..3
  const int m0 = blockIdx.x * 128;

  // staging: thread t covers LDS chunk (row t>>3, slot t&7) [+512-chunk repeats].
  // T2 both-sides: source slot = (t&7) ^ (row&7); reader XORs identically.
  const int swslot = ((tid & 7) ^ ((tid >> 3) & 7)) * 8;
  const int rA = tid >> 3;          // 0..63

  int gA0, gA1;
  {
    int m = m0 + rA; if (m >= M_TOT) m = M_TOT - 1;
    int b = m / 3844; int rem = m - b * 3844;
    int h = rem / 62; int w = rem - h * 62;
    gA0 = ((b * 64 + h) * 64 + w) * 256 + swslot;
    m = m0 + rA + 64; if (m >= M_TOT) m = M_TOT - 1;
    b = m / 3844; rem = m - b * 3844;
    h = rem / 62; w = rem - h * 62;
    gA1 = ((b * 64 + h) * 64 + w) * 256 + swslot;
  }

  f32x4 zero = {0.f, 0.f, 0.f, 0.f};
  f32x4 acc[4][4];
#pragma unroll
  for (int i = 0; i < 4; ++i)
#pragma unroll
    for (int j = 0; j < 4; ++j) acc[i][j] = zero;

  const int rl = lane & 15;
  const int kg = lane >> 4;
  const int xm = (lane & 7) << 4;   // read-side XOR: (row&7)<<4, row&7 == lane&7

#define STAGE(t, buf)                                                            \
  {                                                                              \
    int kk_ = (t) >> 2, cb_ = (t) & 3;                                           \
    int kh_ = kk_ / 3, kw_ = kk_ - kh_ * 3;                                      \
    int offA_ = kh_ * 16384 + kw_ * 256 + cb_ * 64;                              \
    int offB_ = kk_ * 65536 + cb_ * 64 + swslot;                                 \
    gload16(xb + gA0 + offA_, &ldsA[buf][tid * 8]);                              \
    gload16(xb + gA1 + offA_, &ldsA[buf][(tid + 512) * 8]);                      \
    _Pragma("unroll")                                                            \
    for (int q = 0; q < 4; ++q)                                                  \
      gload16(K2t + offB_ + (rA + 64 * q) * 256, &ldsB[buf][(tid + 512 * q) * 8]); \
  }

  STAGE(0, 0);
  __syncthreads();

  for (int t = 0; t < 36; ++t) {
    int buf = t & 1;
    if (t < 35) STAGE(t + 1, buf ^ 1);   // in flight during compute(t)

    bf16x8 af[4][2], bfr[4][2];
#pragma unroll
    for (int mi = 0; mi < 4; ++mi) {
      int rb = (wm * 64 + mi * 16 + rl) * 128;
#pragma unroll
      for (int ks = 0; ks < 2; ++ks) {
        int cbyte = (ks * 64 + kg * 16) ^ xm;
        af[mi][ks] = *(const bf16x8*)((const char*)ldsA[buf] + rb + cbyte);
      }
    }
#pragma unroll
    for (int ni = 0; ni < 4; ++ni) {
      int rb = (wn * 64 + ni * 16 + rl) * 128;
#pragma unroll
      for (int ks = 0; ks < 2; ++ks) {
        int cbyte = (ks * 64 + kg * 16) ^ xm;
        bfr[ni][ks] = *(const bf16x8*)((const char*)ldsB[buf] + rb + cbyte);
      }
    }
#pragma unroll
    for (int ks = 0; ks < 2; ++ks)
#pragma unroll
      for (int mi = 0; mi < 4; ++mi)
#pragma unroll
        for (int ni = 0; ni < 4; ++ni)
          acc[mi][ni] = __builtin_amdgcn_mfma_f32_16x16x32_bf16(
              af[mi][ks], bfr[ni][ks], acc[mi][ni], 0, 0, 0);

    __syncthreads();   // drains STAGE(t+1); also protects buf before overwrite at t+1
  }

  // epilogue: D row = kg*4 + r (+16*mi +64*wm), col = rl (+16*ni +64*wn)
#pragma unroll
  for (int mi = 0; mi < 4; ++mi) {
    int mb = m0 + wm * 64 + mi * 16 + kg * 4;
#pragma unroll
    for (int ni = 0; ni < 4; ++ni) {
      int f = wn * 64 + ni * 16 + rl;
#pragma unroll
      for (int r = 0; r < 4; ++r) {
        int m = mb + r;
        if (m < M_TOT) out[m * 256 + f] = acc[mi][ni][r];
      }
    }
  }
#undef STAGE
}

extern "C" void kernel_launch(void* const* d_in, const int* in_sizes, int n_in,
                              void* d_out, int out_size, void* d_ws, size_t ws_size,
                              hipStream_t stream) {
  const float* x = (const float*)d_in[0];   // [8,64,64,256]
  const float* P = (const float*)d_in[1];   // [256,256]
  const float* Q = (const float*)d_in[2];   // [256,3,3,16]
  const float* S = (const float*)d_in[3];   // [256,16,256]
  float* out = (float*)d_out;               // [8,62,62,256]

  char* ws = (char*)d_ws;
  unsigned short* xb   = (unsigned short*)ws;                        // 16,777,216 B
  float*          Keff = (float*)(ws + 16777216);                    //  2,359,296 B
  unsigned short* K2t  = (unsigned short*)(ws + 16777216 + 2359296); //  1,179,648 B

  cast_x<<<4096, 256, 0, stream>>>(x, xb);
  keff_k<<<2304, 256, 0, stream>>>(Q, S, Keff);
  k2t_k<<<144, 256, 0, stream>>>(P, Keff, K2t);
  conv_gemm<<<241, 512, 0, stream>>>(xb, K2t, out);
}

// Round 5
// 87.325 us; speedup vs baseline: 2.0947x; 1.1599x over previous
//
#include <hip/hip_runtime.h>
#include <hip/hip_bf16.h>

typedef __attribute__((ext_vector_type(4))) float f32x4;
typedef __attribute__((ext_vector_type(8))) short bf16x8;

#define M_TOT 30752   // 8*62*62 output pixels

__device__ __forceinline__ unsigned short f2bf(float f) {
  unsigned int u = __float_as_uint(f);
  u = u + 0x7FFF + ((u >> 16) & 1);   // round-to-nearest-even
  return (unsigned short)(u >> 16);
}

__device__ __forceinline__ void gload16(const void* g, void* l) {
  __builtin_amdgcn_global_load_lds((const __attribute__((address_space(1))) unsigned int*)g,
                                   (__attribute__((address_space(3))) unsigned int*)l,
                                   16, 0, 0);
}

// ---- prep 1: cast x (fp32) -> bf16, 8 elems/thread ----
__global__ void cast_x(const float* __restrict__ x, unsigned short* __restrict__ xb) {
  int i = blockIdx.x * 256 + threadIdx.x;
  const f32x4* xp = (const f32x4*)x;
  f32x4 a = xp[2 * i];
  f32x4 b = xp[2 * i + 1];
  bf16x8 o;
  o[0] = (short)f2bf(a[0]); o[1] = (short)f2bf(a[1]);
  o[2] = (short)f2bf(a[2]); o[3] = (short)f2bf(a[3]);
  o[4] = (short)f2bf(b[0]); o[5] = (short)f2bf(b[1]);
  o[6] = (short)f2bf(b[2]); o[7] = (short)f2bf(b[3]);
  ((bf16x8*)xb)[i] = o;
}

// ---- prep 2: K_eff[och][kk][f] = sum_bi Q[och,kk,bi] * S[16bi+(och>>4)][och&15][f]
__global__ void keff_k(const float* __restrict__ Q, const float* __restrict__ S,
                       float* __restrict__ Keff) {
  int bid = blockIdx.x;          // = och*9 + kk
  int o = bid / 9;
  int kk = bid - o * 9;
  int f = threadIdx.x;
  int qb = o * 144 + kk * 16;
  int sb = ((o >> 4) * 16 + (o & 15)) * 256 + f;
  float acc = 0.f;
#pragma unroll
  for (int bi = 0; bi < 16; ++bi)
    acc = fmaf(Q[qb + bi], S[sb + bi * 65536], acc);
  Keff[bid * 256 + f] = acc;
}

// ---- prep 3: K2t[kk][f][ci] = sum_o P[o][ci] * Keff[o][kk][f]  (bf16, transposed)
__global__ void k2t_k(const float* __restrict__ P, const float* __restrict__ Keff,
                      unsigned short* __restrict__ K2t) {
  int kk = blockIdx.x >> 4;
  int f0 = (blockIdx.x & 15) * 16;
  int ci = threadIdx.x;
  float acc[16];
#pragma unroll
  for (int j = 0; j < 16; ++j) acc[j] = 0.f;
  for (int o = 0; o < 256; ++o) {
    float pv = P[o * 256 + ci];
    const float* ke = Keff + (o * 9 + kk) * 256 + f0;
#pragma unroll
    for (int j = 0; j < 16; ++j) acc[j] = fmaf(pv, ke[j], acc[j]);
  }
#pragma unroll
  for (int j = 0; j < 16; ++j)
    K2t[kk * 65536 + (f0 + j) * 256 + ci] = f2bf(acc[j]);
}

// ---- main: implicit-GEMM conv.  M=30752, N=256 (full), K=2304 (9 taps x 256 ch)
// BM=128, BN=256, BK=64. 512 thr (8 waves, 2m x 4n), 64x64 out per wave.
// TRIPLE-buffered, depth-2 prefetch, COUNTED vmcnt (T3+T4): per K-step
//   asm s_waitcnt vmcnt(6)  [stage(t) landed, stage(t+1) stays in flight]
//   raw s_barrier           [no drain]
//   STAGE(t+2) -> buf (t+2)%3
//   compute(t) from buf t%3
// No vmcnt(0) drain in the main loop.
__global__ __launch_bounds__(512) void conv_gemm(const unsigned short* __restrict__ xb,
                                                 const unsigned short* __restrict__ K2t,
                                                 float* __restrict__ out) {
  __shared__ unsigned short A0[128 * 64];   // 16KB each, XOR-swizzled
  __shared__ unsigned short A1[128 * 64];
  __shared__ unsigned short A2[128 * 64];
  __shared__ unsigned short B0[256 * 64];   // 32KB each, XOR-swizzled
  __shared__ unsigned short B1[256 * 64];
  __shared__ unsigned short B2[256 * 64];

  const int tid = threadIdx.x;
  const int lane = tid & 63;
  const int wm = (tid >> 6) >> 2;   // 0..1
  const int wn = (tid >> 6) & 3;    // 0..3
  const int m0 = blockIdx.x * 128;

  // staging: thread t covers LDS chunk (row t>>3, slot t&7) [+512-chunk repeats].
  // T2 both-sides: source slot = (t&7) ^ (row&7); reader XORs identically.
  const int swslot = ((tid & 7) ^ ((tid >> 3) & 7)) * 8;
  const int rA = tid >> 3;          // 0..63

  int gA0, gA1;
  {
    int m = m0 + rA; if (m >= M_TOT) m = M_TOT - 1;
    int b = m / 3844; int rem = m - b * 3844;
    int h = rem / 62; int w = rem - h * 62;
    gA0 = ((b * 64 + h) * 64 + w) * 256 + swslot;
    m = m0 + rA + 64; if (m >= M_TOT) m = M_TOT - 1;
    b = m / 3844; rem = m - b * 3844;
    h = rem / 62; w = rem - h * 62;
    gA1 = ((b * 64 + h) * 64 + w) * 256 + swslot;
  }

  f32x4 zero = {0.f, 0.f, 0.f, 0.f};
  f32x4 acc[4][4];
#pragma unroll
  for (int i = 0; i < 4; ++i)
#pragma unroll
    for (int j = 0; j < 4; ++j) acc[i][j] = zero;

  const int rl = lane & 15;
  const int kg = lane >> 4;
  const int xm = (lane & 7) << 4;   // read-side XOR: (row&7)<<4, row&7 == lane&7

#define STAGE(t, bufA, bufB)                                                   \
  {                                                                            \
    int kk_ = (t) >> 2, cb_ = (t) & 3;                                         \
    int kh_ = kk_ / 3, kw_ = kk_ - kh_ * 3;                                    \
    int offA_ = kh_ * 16384 + kw_ * 256 + cb_ * 64;                            \
    int offB_ = kk_ * 65536 + cb_ * 64 + swslot;                               \
    gload16(xb + gA0 + offA_, &bufA[tid * 8]);                                 \
    gload16(xb + gA1 + offA_, &bufA[(tid + 512) * 8]);                         \
    _Pragma("unroll")                                                          \
    for (int q = 0; q < 4; ++q)                                                \
      gload16(K2t + offB_ + (rA + 64 * q) * 256, &bufB[(tid + 512 * q) * 8]);  \
  }

#define WAIT_BAR(t)                                                            \
  {                                                                            \
    if ((t) == 35) asm volatile("s_waitcnt vmcnt(0)" ::: "memory");            \
    else           asm volatile("s_waitcnt vmcnt(6)" ::: "memory");            \
    __builtin_amdgcn_sched_barrier(0);                                         \
    __builtin_amdgcn_s_barrier();                                              \
    __builtin_amdgcn_sched_barrier(0);                                         \
  }

#define COMPUTE(t, bufA, bufB)                                                 \
  {                                                                            \
    bf16x8 af[4][2], bfr[4][2];                                                \
    _Pragma("unroll")                                                          \
    for (int mi = 0; mi < 4; ++mi) {                                           \
      int rb = (wm * 64 + mi * 16 + rl) * 128;                                 \
      _Pragma("unroll")                                                        \
      for (int ks = 0; ks < 2; ++ks) {                                         \
        int cbyte = (ks * 64 + kg * 16) ^ xm;                                  \
        af[mi][ks] = *(const bf16x8*)((const char*)bufA + rb + cbyte);         \
      }                                                                        \
    }                                                                          \
    _Pragma("unroll")                                                          \
    for (int ni = 0; ni < 4; ++ni) {                                           \
      int rb = (wn * 64 + ni * 16 + rl) * 128;                                 \
      _Pragma("unroll")                                                        \
      for (int ks = 0; ks < 2; ++ks) {                                         \
        int cbyte = (ks * 64 + kg * 16) ^ xm;                                  \
        bfr[ni][ks] = *(const bf16x8*)((const char*)bufB + rb + cbyte);        \
      }                                                                        \
    }                                                                          \
    _Pragma("unroll")                                                          \
    for (int ks = 0; ks < 2; ++ks)                                             \
      _Pragma("unroll")                                                        \
      for (int mi = 0; mi < 4; ++mi)                                           \
        _Pragma("unroll")                                                      \
        for (int ni = 0; ni < 4; ++ni)                                         \
          acc[mi][ni] = __builtin_amdgcn_mfma_f32_16x16x32_bf16(               \
              af[mi][ks], bfr[ni][ks], acc[mi][ni], 0, 0, 0);                  \
  }

  STAGE(0, A0, B0);
  STAGE(1, A1, B1);

  for (int tt = 0; tt < 12; ++tt) {
    int t0 = tt * 3;
    WAIT_BAR(t0);
    if (t0 + 2 < 36) STAGE(t0 + 2, A2, B2);
    __builtin_amdgcn_sched_barrier(0);
    COMPUTE(t0, A0, B0);

    WAIT_BAR(t0 + 1);
    if (t0 + 3 < 36) STAGE(t0 + 3, A0, B0);
    __builtin_amdgcn_sched_barrier(0);
    COMPUTE(t0 + 1, A1, B1);

    WAIT_BAR(t0 + 2);
    if (t0 + 4 < 36) STAGE(t0 + 4, A1, B1);
    __builtin_amdgcn_sched_barrier(0);
    COMPUTE(t0 + 2, A2, B2);
  }

  // epilogue: D row = kg*4 + r (+16*mi +64*wm), col = rl (+16*ni +64*wn)
#pragma unroll
  for (int mi = 0; mi < 4; ++mi) {
    int mb = m0 + wm * 64 + mi * 16 + kg * 4;
#pragma unroll
    for (int ni = 0; ni < 4; ++ni) {
      int f = wn * 64 + ni * 16 + rl;
#pragma unroll
      for (int r = 0; r < 4; ++r) {
        int m = mb + r;
        if (m < M_TOT) out[m * 256 + f] = acc[mi][ni][r];
      }
    }
  }
#undef STAGE
#undef WAIT_BAR
#undef COMPUTE
}

extern "C" void kernel_launch(void* const* d_in, const int* in_sizes, int n_in,
                              void* d_out, int out_size, void* d_ws, size_t ws_size,
                              hipStream_t stream) {
  const float* x = (const float*)d_in[0];   // [8,64,64,256]
  const float* P = (const float*)d_in[1];   // [256,256]
  const float* Q = (const float*)d_in[2];   // [256,3,3,16]
  const float* S = (const float*)d_in[3];   // [256,16,256]
  float* out = (float*)d_out;               // [8,62,62,256]

  char* ws = (char*)d_ws;
  unsigned short* xb   = (unsigned short*)ws;                        // 16,777,216 B
  float*          Keff = (float*)(ws + 16777216);                    //  2,359,296 B
  unsigned short* K2t  = (unsigned short*)(ws + 16777216 + 2359296); //  1,179,648 B

  cast_x<<<4096, 256, 0, stream>>>(x, xb);
  keff_k<<<2304, 256, 0, stream>>>(Q, S, Keff);
  k2t_k<<<144, 256, 0, stream>>>(P, Keff, K2t);
  conv_gemm<<<241, 512, 0, stream>>>(xb, K2t, out);
}